// Round 1
// baseline (916.798 us; speedup 1.0000x reference)
//
#include <hip/hip_runtime.h>

// Problem constants (match reference)
constexpr int B_SZ     = 4096;
constexpr int F_REG    = 25;
constexpr int F_CMP    = 25;
constexpr int F_TOT    = F_REG + F_CMP;   // 50
constexpr int L_LEN    = 20;
constexpr int D_DIM    = 64;
constexpr int V_REG    = 50000;           // reg table rows = V_REG+1
constexpr int N_BUCKET = 100000;          // cmp table rows = N_BUCKET+1

constexpr int WAVES_PER_BLOCK = 4;        // 256 threads = 4 waves, 1 bag/wave

__global__ __launch_bounds__(256)
void embed_bag_kernel(const int* __restrict__ feats,     // [B, 50*20]
                      const float* __restrict__ Wreg,    // [25, 50001, 64]
                      const float* __restrict__ Wcmp,    // [25, 100001, 64]
                      float* __restrict__ out)           // [B, 50, 64]
{
    const int lane = threadIdx.x & 63;
    const int wave = threadIdx.x >> 6;
    const int bag  = blockIdx.x * WAVES_PER_BLOCK + wave;   // [0, B*50)
    if (bag >= B_SZ * F_TOT) return;

    const int b = bag / F_TOT;
    const int f = bag - b * F_TOT;

    // ---- load + transform this bag's 20 indices (lanes 0..19) ----
    const int* bag_feats = feats + (size_t)b * (F_TOT * L_LEN) + f * L_LEN;
    int idx = 0;
    if (lane < L_LEN) {
        int v = bag_feats[lane];
        if (f < F_REG) {
            // clamp(0, V_REG)
            idx = min(max(v, 0), V_REG);
        } else {
            // clamp_min(0), then hash-compress: v>0 -> (v-1)%N + 1, else 0
            v = max(v, 0);
            idx = (v > 0) ? ((v - 1) % N_BUCKET + 1) : 0;
        }
    }

    // nonzero count for mean (>=1)
    unsigned long long nz = __ballot(lane < L_LEN && idx > 0);
    int cnt = __popcll(nz);
    float cntf = (float)(cnt > 0 ? cnt : 1);

    // ---- gather + accumulate: lane owns element d = lane ----
    const float* table = (f < F_REG)
        ? (Wreg + (size_t)f * (size_t)(V_REG + 1) * D_DIM)
        : (Wcmp + (size_t)(f - F_REG) * (size_t)(N_BUCKET + 1) * D_DIM);

    float acc = 0.0f;
    #pragma unroll
    for (int l = 0; l < L_LEN; ++l) {
        int rl = __shfl(idx, l, 64);                 // wave-uniform row id
        acc += table[(size_t)rl * D_DIM + lane];     // 256B coalesced per row
    }

    out[(size_t)bag * D_DIM + lane] = acc / cntf;
}

extern "C" void kernel_launch(void* const* d_in, const int* in_sizes, int n_in,
                              void* d_out, int out_size, void* d_ws, size_t ws_size,
                              hipStream_t stream) {
    const int*   feats = (const int*)d_in[0];
    const float* Wreg  = (const float*)d_in[1];
    const float* Wcmp  = (const float*)d_in[2];
    float*       out   = (float*)d_out;

    const int n_bags = B_SZ * F_TOT;                         // 204800
    const int grid   = n_bags / WAVES_PER_BLOCK;             // 51200 blocks
    embed_bag_kernel<<<grid, 256, 0, stream>>>(feats, Wreg, Wcmp, out);
}

// Round 2
// 914.286 us; speedup vs baseline: 1.0027x; 1.0027x over previous
//
#include <hip/hip_runtime.h>

// Problem constants (match reference)
constexpr int F_REG    = 25;
constexpr int F_CMP    = 25;
constexpr int F_TOT    = F_REG + F_CMP;   // 50
constexpr int L_LEN    = 20;
constexpr int D_DIM    = 64;
constexpr int V_REG    = 50000;           // reg table rows = V_REG+1
constexpr int N_BUCKET = 100000;          // cmp table rows = N_BUCKET+1

constexpr int BAGS_PER_BLOCK = 16;        // 256 thr = 4 waves x 4 quarter-waves, 1 bag each

__global__ __launch_bounds__(256)
void embed_bag_kernel(const int* __restrict__ feats,     // [B, 50*20]
                      const float* __restrict__ Wreg,    // [25, 50001, 64]
                      const float* __restrict__ Wcmp,    // [25, 100001, 64]
                      float* __restrict__ out)           // [B, 50, 64]
{
    __shared__ int s_idx[BAGS_PER_BLOCK * L_LEN];        // 320 ints

    const int tid        = threadIdx.x;
    const int block_bag0 = blockIdx.x * BAGS_PER_BLOCK;  // first bag of this block

    // ---- cooperative load + transform of the block's 320 indices ----
    // feats address for (bag, pos) is bag*20 + pos  ->  contiguous slab per block
    for (int s = tid; s < BAGS_PER_BLOCK * L_LEN; s += 256) {
        int v = feats[(size_t)block_bag0 * L_LEN + s];
        const int f = (block_bag0 + s / L_LEN) % F_TOT;
        int idx;
        if (f < F_REG) {
            idx = min(max(v, 0), V_REG);                 // clamp(0, V_REG)
        } else {
            v = max(v, 0);                               // clamp_min(0)
            idx = (v > 0) ? ((v - 1) % N_BUCKET + 1) : 0;
        }
        s_idx[s] = idx;
    }
    __syncthreads();

    // ---- one bag per quarter-wave; lane owns 4 consecutive floats of D ----
    const int lane      = tid & 63;
    const int wave      = tid >> 6;
    const int q         = lane >> 4;                     // quarter within wave
    const int lane16    = lane & 15;                     // 16 lanes x float4 = 256B row
    const int bag_local = wave * 4 + q;
    const int bag       = block_bag0 + bag_local;        // grid sized exactly: no guard

    const int f = bag % F_TOT;
    const float* tbl = (f < F_REG)
        ? Wreg + (size_t)f           * (size_t)(V_REG    + 1) * D_DIM
        : Wcmp + (size_t)(f - F_REG) * (size_t)(N_BUCKET + 1) * D_DIM;

    // pull this bag's 20 rows into registers (quarter-uniform LDS broadcast)
    int rows[L_LEN];
    #pragma unroll
    for (int l = 0; l < L_LEN; ++l)
        rows[l] = s_idx[bag_local * L_LEN + l];

    int cnt = 0;
    #pragma unroll
    for (int l = 0; l < L_LEN; ++l)
        cnt += (rows[l] > 0);

    // 20 independent 16B gathers, all issued back-to-back -> 320B/lane in flight
    float4 acc = {0.0f, 0.0f, 0.0f, 0.0f};
    #pragma unroll
    for (int l = 0; l < L_LEN; ++l) {
        const float4 v = *reinterpret_cast<const float4*>(
            tbl + (size_t)rows[l] * D_DIM + lane16 * 4);
        acc.x += v.x; acc.y += v.y; acc.z += v.z; acc.w += v.w;
    }

    const float inv = 1.0f / (float)(cnt > 0 ? cnt : 1);
    float4 r = {acc.x * inv, acc.y * inv, acc.z * inv, acc.w * inv};
    *reinterpret_cast<float4*>(out + (size_t)bag * D_DIM + lane16 * 4) = r;
}

extern "C" void kernel_launch(void* const* d_in, const int* in_sizes, int n_in,
                              void* d_out, int out_size, void* d_ws, size_t ws_size,
                              hipStream_t stream) {
    const int*   feats = (const int*)d_in[0];
    const float* Wreg  = (const float*)d_in[1];
    const float* Wcmp  = (const float*)d_in[2];
    float*       out   = (float*)d_out;

    const int n_bags = out_size / D_DIM;                 // 4096*50 = 204800
    const int grid   = n_bags / BAGS_PER_BLOCK;          // 12800 blocks
    embed_bag_kernel<<<grid, 256, 0, stream>>>(feats, Wreg, Wcmp, out);
}